// Round 1
// 610.564 us; speedup vs baseline: 1.0149x; 1.0149x over previous
//
#include <hip/hip_runtime.h>
#include <math.h>

#define N_USERS 60000
#define N_ITEMS 30000
#define N_NODES 90000
#define DD 64
#define FF 192              // 3*DD
#define FH 96               // FF/2 (bf16 pairs per row)
#define KK_TOT 1408         // 768 + 512 + 128
#define E_UND 500000
#define E_DIR 1000000
#define SCAN_NBLK 88        // ceil(90000/1024)

typedef __attribute__((ext_vector_type(8))) __bf16 bf16x8;
typedef __attribute__((ext_vector_type(8))) unsigned short u16x8;
typedef __attribute__((ext_vector_type(4))) float f32x4;

__device__ __forceinline__ unsigned short f2bf(float f) {
    unsigned int u = __float_as_uint(f);
    unsigned int r = (u + 0x7FFFu + ((u >> 16) & 1u)) >> 16;   // RNE
    return (unsigned short)r;
}
__device__ __forceinline__ float bf_lo(unsigned int x) { return __uint_as_float(x << 16); }
__device__ __forceinline__ float bf_hi(unsigned int x) { return __uint_as_float(x & 0xFFFF0000u); }
__device__ __forceinline__ float bf2f(unsigned short x) {
    return __uint_as_float((unsigned int)x << 16);
}
__device__ __forceinline__ unsigned int pack2(float a, float b) {
    return ((unsigned int)f2bf(b) << 16) | (unsigned int)f2bf(a);
}

// ---------------- edge-layout probe: int32 vs int64 storage ----------------
__global__ void k_mode(const int* __restrict__ ei, int* __restrict__ mode) {
    __shared__ int any;
    if (threadIdx.x == 0) any = 0;
    __syncthreads();
    if (ei[2 * threadIdx.x + 1] != 0) atomicOr(&any, 1);
    __syncthreads();
    if (threadIdx.x == 0) mode[0] = (any == 0) ? 1 : 0;   // 1 => int64 layout
}

__device__ __forceinline__ void load_pair(const int* __restrict__ ei, int md, int u,
                                          int& a, int& b) {
    if (md) { a = ei[2 * u]; b = ei[2 * (E_UND + u)]; }
    else    { a = ei[u];     b = ei[E_UND + u]; }
}

// ---------------- degree count ----------------
__global__ void k_deg(const int* __restrict__ ei, const int* __restrict__ mode,
                      int* __restrict__ deg) {
    int i = blockIdx.x * 256 + threadIdx.x;
    if (i >= E_UND) return;
    int md = mode[0];
    int a, b;
    load_pair(ei, md, i, a, b);
    atomicAdd(&deg[a], 1);
    atomicAdd(&deg[b], 1);
}

// ---------------- exclusive scan (3 kernels) ----------------
__global__ __launch_bounds__(1024) void k_scan1(const int* __restrict__ deg,
                                                int* __restrict__ offs,
                                                int* __restrict__ bsum) {
    __shared__ int tmp[1024];
    int b = blockIdx.x, t = threadIdx.x;
    int i = b * 1024 + t;
    int v = (i < N_NODES) ? deg[i] : 0;
    tmp[t] = v;
    __syncthreads();
    for (int off = 1; off < 1024; off <<= 1) {
        int add = (t >= off) ? tmp[t - off] : 0;
        __syncthreads();
        tmp[t] += add;
        __syncthreads();
    }
    offs[i] = tmp[t] - v;              // exclusive within block
    if (t == 1023) bsum[b] = tmp[t];
}

__global__ void k_scan2(const int* __restrict__ bsum, int* __restrict__ bscan) {
    if (threadIdx.x == 0) {
        int run = 0;
        for (int b = 0; b < SCAN_NBLK; b++) { bscan[b] = run; run += bsum[b]; }
    }
}

__global__ void k_scan3(const int* __restrict__ deg, int* __restrict__ offs,
                        const int* __restrict__ bscan, int* __restrict__ cursor,
                        float* __restrict__ rsq) {
    int i = blockIdx.x * 256 + threadIdx.x;
    if (i >= N_NODES) return;
    int o = offs[i] + bscan[i >> 10];
    offs[i] = o;
    cursor[i] = o;
    int dg = deg[i];
    if (dg < 1) dg = 1;
    rsq[i] = rsqrtf((float)dg);
}

// ---------------- CSR fill (counting-sort scatter) ----------------
__global__ void k_fill(const int* __restrict__ ei, const int* __restrict__ mode,
                       int* __restrict__ cursor, const float* __restrict__ rsq,
                       int* __restrict__ edst, float* __restrict__ eval) {
    int i = blockIdx.x * 256 + threadIdx.x;
    if (i >= E_DIR) return;
    int md = mode[0];
    int u = (i < E_UND) ? i : i - E_UND;
    int a, b;
    load_pair(ei, md, u, a, b);
    int s, d;
    if (i < E_UND) { s = a; d = b; } else { s = b; d = a; }
    int slot = atomicAdd(&cursor[s], 1);
    edst[slot] = d;
    eval[slot] = rsq[s] * rsq[d];
}

// ---------------- user rows: transpose copy into bf16 Xb ----------------
__global__ void k_users(const float* __restrict__ ue, unsigned short* __restrict__ Xbs) {
    int idx = blockIdx.x * 256 + threadIdx.x;
    if (idx >= N_USERS * FF) return;
    int n = idx / FF;
    int r = idx - n * FF;
    int b = r >> 6, d = r & 63;
    Xbs[idx] = f2bf(ue[((size_t)b * N_USERS + n) * DD + d]);
}

// ---------------- W transpose+concat+bf16: Wtb[n][k], n=b*64+d ----------------
__global__ void k_cvt_w(const float* __restrict__ Wt, const float* __restrict__ Wi,
                        const float* __restrict__ Wst, unsigned short* __restrict__ Wtb) {
    int idx = blockIdx.x * 256 + threadIdx.x;
    if (idx >= FF * KK_TOT) return;
    int n = idx / KK_TOT;
    int k = idx - n * KK_TOT;
    int b = n >> 6, d = n & 63;
    float v;
    if (k < 768)       v = Wt [((size_t)b * 768 + k) * 64 + d];
    else if (k < 1280) v = Wi [((size_t)b * 512 + (k - 768)) * 64 + d];
    else               v = Wst[((size_t)b * 128 + (k - 1280)) * 64 + d];
    Wtb[idx] = f2bf(v);
}

// ---------------- W1 transpose to bf16: W1T[n][k] = W1[k][n], 128x192 -------
__global__ void k_cvt_w1(const float* __restrict__ Wu1, const float* __restrict__ Wi1,
                         unsigned short* __restrict__ W1Tu,
                         unsigned short* __restrict__ W1Ti) {
    int idx = blockIdx.x * 256 + threadIdx.x;
    if (idx >= 128 * FF) return;
    int n = idx / FF;
    int k = idx - n * FF;
    W1Tu[idx] = f2bf(Wu1[(size_t)k * 128 + n]);
    W1Ti[idx] = f2bf(Wi1[(size_t)k * 128 + n]);
}

// ---------------- item feature GEMM: BM=64, N split in 2, paired dispatch --
// Double-buffered LDS + 1-deep register prefetch (T3 2-phase + T14 split):
// loads for K-tile t+1 are issued before the barrier of tile t, so HBM
// latency is covered by the MFMA phase instead of serializing each K-step.
#define BM 64
#define BNH 96
#define BK 64
#define LDK 72   // padded LDS pitch (elements)

__global__ __launch_bounds__(256) void k_item_gemm_mfma3(
    const float* __restrict__ xt, const float* __restrict__ xi, const float* __restrict__ xs,
    const unsigned short* __restrict__ Wtb,
    const float* __restrict__ bt, const float* __restrict__ bi, const float* __restrict__ bst,
    unsigned short* __restrict__ Xbs) {
    __shared__ unsigned short Ash[2][BM * LDK];      // 2 x 9.2 KB
    __shared__ unsigned short Bsh[2][BNH * LDK];     // 2 x 13.8 KB
    const int tid  = threadIdx.x;
    const int wave = tid >> 6;
    const int lane = tid & 63;
    const int row0 = (blockIdx.x >> 1) * BM;
    const int n0   = (blockIdx.x & 1) * BNH;

    // staging layout: thread t handles row sr (+32 per chunk), 8-elem col sc
    const int sr = tid >> 3;            // 0..31
    const int sc = (tid & 7) << 3;      // 0,8,...,56

    // clamp OOB rows to last row: duplicate data, C-write is guarded
    int gr0 = row0 + sr;        if (gr0 >= N_ITEMS) gr0 = N_ITEMS - 1;
    int gr1 = row0 + sr + 32;   if (gr1 >= N_ITEMS) gr1 = N_ITEMS - 1;

    const size_t bbase = (size_t)(n0 + sr) * KK_TOT + sc;

    float4 pa[2][2];    // prefetch regs: A rows {sr, sr+32}, 8 floats each
    u16x8  pb[3];       // prefetch regs: B rows {sr, sr+32, sr+64}

    // issue global loads for K-tile starting at k0 (whole 64-wide tile lies
    // inside one source region since region sizes are multiples of 64)
    auto issue = [&](int k0) {
        int kl = k0 + sc;
        const float *s0, *s1;
        if (kl < 768)       { s0 = xt + (size_t)gr0 * 768 + kl;
                              s1 = xt + (size_t)gr1 * 768 + kl; }
        else if (kl < 1280) { s0 = xi + (size_t)gr0 * 512 + (kl - 768);
                              s1 = xi + (size_t)gr1 * 512 + (kl - 768); }
        else                { s0 = xs + (size_t)gr0 * 128 + (kl - 1280);
                              s1 = xs + (size_t)gr1 * 128 + (kl - 1280); }
        pa[0][0] = *(const float4*)(s0);
        pa[0][1] = *(const float4*)(s0 + 4);
        pa[1][0] = *(const float4*)(s1);
        pa[1][1] = *(const float4*)(s1 + 4);
        pb[0] = *(const u16x8*)(&Wtb[bbase + k0]);
        pb[1] = *(const u16x8*)(&Wtb[bbase + k0 + (size_t)32 * KK_TOT]);
        pb[2] = *(const u16x8*)(&Wtb[bbase + k0 + (size_t)64 * KK_TOT]);
    };

    f32x4 acc[6];
#pragma unroll
    for (int tn = 0; tn < 6; tn++) acc[tn] = (f32x4){0.f, 0.f, 0.f, 0.f};

    const int l16  = lane & 15;
    const int quad = lane >> 4;

    issue(0);
    int cur = 0;
    for (int k0 = 0; k0 < KK_TOT; k0 += BK) {
        // drain this tile's loads (implicit vmcnt wait on pa/pb), cvt, stage
#pragma unroll
        for (int i = 0; i < 2; i++) {
            u16x8 pk;
            pk[0] = f2bf(pa[i][0].x); pk[1] = f2bf(pa[i][0].y);
            pk[2] = f2bf(pa[i][0].z); pk[3] = f2bf(pa[i][0].w);
            pk[4] = f2bf(pa[i][1].x); pk[5] = f2bf(pa[i][1].y);
            pk[6] = f2bf(pa[i][1].z); pk[7] = f2bf(pa[i][1].w);
            *(u16x8*)(&Ash[cur][(sr + i * 32) * LDK + sc]) = pk;
        }
#pragma unroll
        for (int i = 0; i < 3; i++)
            *(u16x8*)(&Bsh[cur][(sr + i * 32) * LDK + sc]) = pb[i];

        // prefetch next tile — stays in flight across the barrier + MFMAs
        if (k0 + BK < KK_TOT) issue(k0 + BK);

        __syncthreads();   // single barrier per K-step: dbuf removes the WAR one

#pragma unroll
        for (int kk = 0; kk < BK; kk += 32) {
            bf16x8 af = *(const bf16x8*)(&Ash[cur][(wave * 16 + l16) * LDK + kk + quad * 8]);
#pragma unroll
            for (int tn = 0; tn < 6; tn++) {
                bf16x8 bfr = *(const bf16x8*)(&Bsh[cur][(tn * 16 + l16) * LDK + kk + quad * 8]);
                acc[tn] = __builtin_amdgcn_mfma_f32_16x16x32_bf16(af, bfr, acc[tn], 0, 0, 0);
            }
        }
        cur ^= 1;
    }

#pragma unroll
    for (int tn = 0; tn < 6; tn++) {
        int n = n0 + tn * 16 + l16;         // 0..191
        int b = n >> 6, d = n & 63;
        float bias = bt[b * 64 + d] + bi[b * 64 + d] + bst[b * 64 + d];
#pragma unroll
        for (int r = 0; r < 4; r++) {
            int row = row0 + wave * 16 + quad * 4 + r;
            if (row < N_ITEMS) {
                Xbs[(size_t)(N_USERS + row) * FF + n] = f2bf(acc[tn][r] + bias);
            }
        }
    }
}

// ---------------- SPMM bf16 gather, 4-wide unroll ----------------
__global__ __launch_bounds__(192) void k_spmm_bf(const unsigned int* __restrict__ Xb,
                                                 unsigned int* __restrict__ Yb,
                                                 const int* __restrict__ offs,
                                                 const int* __restrict__ deg,
                                                 const int* __restrict__ edst,
                                                 const float* __restrict__ eval) {
    int t = threadIdx.x;
    int half = (t >= FH) ? 1 : 0;
    int c = t - half * FH;
    int n = blockIdx.x * 2 + half;
    int start = offs[n];
    int dg = deg[n];
    const int* ed = edst + start;
    const float* ev = eval + start;
    float a0 = 0.f, a1 = 0.f;
    for (int j = 0; j < dg; j += 4) {
        int last = dg - 1;
        int j1 = (j + 1 < dg) ? j + 1 : last;
        int j2 = (j + 2 < dg) ? j + 2 : last;
        int j3 = (j + 3 < dg) ? j + 3 : last;
        int d0 = ed[j], d1 = ed[j1], d2 = ed[j2], d3 = ed[j3];
        float v0 = ev[j];
        float v1 = (j + 1 < dg) ? ev[j1] : 0.f;
        float v2 = (j + 2 < dg) ? ev[j2] : 0.f;
        float v3 = (j + 3 < dg) ? ev[j3] : 0.f;
        unsigned int x0 = Xb[(size_t)d0 * FH + c];
        unsigned int x1 = Xb[(size_t)d1 * FH + c];
        unsigned int x2 = Xb[(size_t)d2 * FH + c];
        unsigned int x3 = Xb[(size_t)d3 * FH + c];
        a0 = fmaf(v0, bf_lo(x0), a0); a1 = fmaf(v0, bf_hi(x0), a1);
        a0 = fmaf(v1, bf_lo(x1), a0); a1 = fmaf(v1, bf_hi(x1), a1);
        a0 = fmaf(v2, bf_lo(x2), a0); a1 = fmaf(v2, bf_hi(x2), a1);
        a0 = fmaf(v3, bf_lo(x3), a0); a1 = fmaf(v3, bf_hi(x3), a1);
    }
    Yb[(size_t)n * FH + c] = pack2(a0, a1);
}

// ---------------- attention: sum 3 bf16 layers + MFMA MLP + readout --------
#define LDA 200

__global__ __launch_bounds__(256) void k_attn_mfma(
    const unsigned int* __restrict__ X0,      // layer-0 bf16 pairs
    const unsigned int* __restrict__ X1,      // layer-1
    const unsigned int* __restrict__ X2,      // layer-2
    const unsigned short* __restrict__ W1T,   // 128 x 192 bf16 (pre-transposed)
    const float* __restrict__ B1,             // 128
    const float* __restrict__ W2,             // 128 x 3
    const float* __restrict__ B2,             // 3
    float* __restrict__ out,
    int node_base, int n_rows) {
    __shared__ unsigned short Atile[64 * LDA];
    __shared__ float aws[64][4];
    const int tid  = threadIdx.x;
    const int wave = tid >> 6;
    const int lane = tid & 63;
    const int row0 = blockIdx.x * 64;
    const float inv3 = 1.f / 3.f;

    // stage A: 64 rows x 96 uint-pairs; sum three bf16 layers in fp32, /3
#pragma unroll
    for (int i = 0; i < 6; i++) {
        int id = tid + i * 256;            // 0..1535
        int r = id / 24;
        int q = id - r * 24;               // uint group: 4 uints = 8 bf16 cols
        u16x8 pk;
        if (row0 + r < n_rows) {
            size_t base = (size_t)(node_base + row0 + r) * FH + q * 4;
            uint4 a = *(const uint4*)(X0 + base);
            uint4 b = *(const uint4*)(X1 + base);
            uint4 c = *(const uint4*)(X2 + base);
            pk[0] = f2bf((bf_lo(a.x) + bf_lo(b.x) + bf_lo(c.x)) * inv3);
            pk[1] = f2bf((bf_hi(a.x) + bf_hi(b.x) + bf_hi(c.x)) * inv3);
            pk[2] = f2bf((bf_lo(a.y) + bf_lo(b.y) + bf_lo(c.y)) * inv3);
            pk[3] = f2bf((bf_hi(a.y) + bf_hi(b.y) + bf_hi(c.y)) * inv3);
            pk[4] = f2bf((bf_lo(a.z) + bf_lo(b.z) + bf_lo(c.z)) * inv3);
            pk[5] = f2bf((bf_hi(a.z) + bf_hi(b.z) + bf_hi(c.z)) * inv3);
            pk[6] = f2bf((bf_lo(a.w) + bf_lo(b.w) + bf_lo(c.w)) * inv3);
            pk[7] = f2bf((bf_hi(a.w) + bf_hi(b.w) + bf_hi(c.w)) * inv3);
        } else {
            pk = (u16x8){0, 0, 0, 0, 0, 0, 0, 0};
        }
        *(u16x8*)(&Atile[r * LDA + q * 8]) = pk;
    }
    __syncthreads();

    f32x4 acc[8];
#pragma unroll
    for (int tn = 0; tn < 8; tn++) acc[tn] = (f32x4){0.f, 0.f, 0.f, 0.f};
    const int l16 = lane & 15;
    const int quad = lane >> 4;
#pragma unroll
    for (int kk = 0; kk < FF; kk += 32) {
        bf16x8 af = *(const bf16x8*)(&Atile[(wave * 16 + l16) * LDA + kk + quad * 8]);
#pragma unroll
        for (int tn = 0; tn < 8; tn++) {
            bf16x8 bf = *(const bf16x8*)(&W1T[(size_t)(tn * 16 + l16) * FF + kk + quad * 8]);
            acc[tn] = __builtin_amdgcn_mfma_f32_16x16x32_bf16(af, bf, acc[tn], 0, 0, 0);
        }
    }

    float pl[4][3];
#pragma unroll
    for (int r = 0; r < 4; r++) { pl[r][0] = 0.f; pl[r][1] = 0.f; pl[r][2] = 0.f; }
#pragma unroll
    for (int tn = 0; tn < 8; tn++) {
        int col = tn * 16 + l16;
        float b1v = B1[col];
        float w0 = W2[col * 3 + 0], w1 = W2[col * 3 + 1], w2v = W2[col * 3 + 2];
#pragma unroll
        for (int r = 0; r < 4; r++) {
            float h = fmaxf(acc[tn][r] + b1v, 0.f);
            pl[r][0] = fmaf(h, w0, pl[r][0]);
            pl[r][1] = fmaf(h, w1, pl[r][1]);
            pl[r][2] = fmaf(h, w2v, pl[r][2]);
        }
    }
#pragma unroll
    for (int m = 1; m <= 8; m <<= 1) {
#pragma unroll
        for (int r = 0; r < 4; r++) {
            pl[r][0] += __shfl_xor(pl[r][0], m, 64);
            pl[r][1] += __shfl_xor(pl[r][1], m, 64);
            pl[r][2] += __shfl_xor(pl[r][2], m, 64);
        }
    }
    float b20 = B2[0], b21 = B2[1], b22 = B2[2];
    if (l16 == 0) {
#pragma unroll
        for (int r = 0; r < 4; r++) {
            float l0 = pl[r][0] + b20, l1 = pl[r][1] + b21, l2 = pl[r][2] + b22;
            float mx = fmaxf(l0, fmaxf(l1, l2));
            float e0 = __expf(l0 - mx), e1 = __expf(l1 - mx), e2 = __expf(l2 - mx);
            float inv = 1.f / (e0 + e1 + e2);
            int rr = wave * 16 + quad * 4 + r;
            aws[rr][0] = e0 * inv; aws[rr][1] = e1 * inv; aws[rr][2] = e2 * inv;
        }
    }
    __syncthreads();

#pragma unroll
    for (int i = 0; i < 16; i++) {
        int flat = tid + i * 256;
        int r = flat >> 6, d = flat & 63;
        if (row0 + r < n_rows) {
            float a0 = aws[r][0], a1 = aws[r][1], a2 = aws[r][2];
            const unsigned short* Ar = &Atile[r * LDA];
            float v = a0 * bf2f(Ar[d]) + a1 * bf2f(Ar[64 + d]) + a2 * bf2f(Ar[128 + d]);
            out[(size_t)(node_base + row0 + r) * DD + d] = v;
        }
    }
}

// ---------------- launch ----------------
extern "C" void kernel_launch(void* const* d_in, const int* in_sizes, int n_in,
                              void* d_out, int out_size, void* d_ws, size_t ws_size,
                              hipStream_t stream) {
    (void)in_sizes; (void)n_in; (void)out_size; (void)ws_size;
    const float* x_txt    = (const float*)d_in[0];
    const float* x_img    = (const float*)d_in[1];
    const float* x_struct = (const float*)d_in[2];
    const float* user_emb = (const float*)d_in[3];
    const float* W_txt    = (const float*)d_in[4];
    const float* b_txt    = (const float*)d_in[5];
    const float* W_img    = (const float*)d_in[6];
    const float* b_img    = (const float*)d_in[7];
    const float* W_st     = (const float*)d_in[8];
    const float* b_st     = (const float*)d_in[9];
    const float* Wu1      = (const float*)d_in[10];
    const float* bu1      = (const float*)d_in[11];
    const float* Wu2      = (const float*)d_in[12];
    const float* bu2      = (const float*)d_in[13];
    const float* Wi1      = (const float*)d_in[14];
    const float* bi1      = (const float*)d_in[15];
    const float* Wi2      = (const float*)d_in[16];
    const float* bi2      = (const float*)d_in[17];
    const int*   ei       = (const int*)d_in[18];
    float* out = (float*)d_out;

    char* base = (char*)d_ws;
    size_t off = 0;
    auto take = [&](size_t bytes) -> void* {
        void* p = base + off;
        off += (bytes + 255) & ~(size_t)255;
        return p;
    };
    unsigned int* Xb0  = (unsigned int*)take((size_t)N_NODES * FH * 4);
    unsigned int* Yb   = (unsigned int*)take((size_t)N_NODES * FH * 4);
    unsigned int* Zb   = (unsigned int*)take((size_t)N_NODES * FH * 4);
    int* deg    = (int*)take((size_t)N_NODES * 4);
    int* offs   = (int*)take((size_t)SCAN_NBLK * 1024 * 4);
    int* cursor = (int*)take((size_t)N_NODES * 4);
    int* bsum   = (int*)take((size_t)SCAN_NBLK * 4);
    int* bscan  = (int*)take((size_t)SCAN_NBLK * 4);
    float* rsq  = (float*)take((size_t)N_NODES * 4);
    int* edst   = (int*)take((size_t)E_DIR * 4);
    float* eval = (float*)take((size_t)E_DIR * 4);
    int* mode   = (int*)take(256);
    unsigned short* Wtb  = (unsigned short*)take((size_t)FF * KK_TOT * 2);
    unsigned short* W1Tu = (unsigned short*)take((size_t)128 * FF * 2);
    unsigned short* W1Ti = (unsigned short*)take((size_t)128 * FF * 2);

    hipMemsetAsync(deg, 0, (size_t)N_NODES * 4, stream);

    k_mode<<<1, 256, 0, stream>>>(ei, mode);
    k_deg<<<(E_UND + 255) / 256, 256, 0, stream>>>(ei, mode, deg);
    k_scan1<<<SCAN_NBLK, 1024, 0, stream>>>(deg, offs, bsum);
    k_scan2<<<1, 64, 0, stream>>>(bsum, bscan);
    k_scan3<<<(N_NODES + 255) / 256, 256, 0, stream>>>(deg, offs, bscan, cursor, rsq);
    k_fill<<<(E_DIR + 255) / 256, 256, 0, stream>>>(ei, mode, cursor, rsq, edst, eval);

    k_users<<<(N_USERS * FF + 255) / 256, 256, 0, stream>>>(user_emb,
                                                            (unsigned short*)Xb0);
    k_cvt_w<<<(FF * KK_TOT + 255) / 256, 256, 0, stream>>>(W_txt, W_img, W_st, Wtb);
    k_cvt_w1<<<(128 * FF + 255) / 256, 256, 0, stream>>>(Wu1, Wi1, W1Tu, W1Ti);
    k_item_gemm_mfma3<<<((N_ITEMS + BM - 1) / BM) * 2, 256, 0, stream>>>(
        x_txt, x_img, x_struct, Wtb, b_txt, b_img, b_st, (unsigned short*)Xb0);

    k_spmm_bf<<<N_NODES / 2, 192, 0, stream>>>(Xb0, Yb, offs, deg, edst, eval);
    k_spmm_bf<<<N_NODES / 2, 192, 0, stream>>>(Yb, Zb, offs, deg, edst, eval);

    k_attn_mfma<<<(N_USERS + 63) / 64, 256, 0, stream>>>(
        Xb0, Yb, Zb, W1Tu, bu1, Wu2, bu2, out, 0, N_USERS);
    k_attn_mfma<<<(N_ITEMS + 63) / 64, 256, 0, stream>>>(
        Xb0, Yb, Zb, W1Ti, bi1, Wi2, bi2, out, N_USERS, N_ITEMS);
}

// Round 3
// 604.402 us; speedup vs baseline: 1.0253x; 1.0102x over previous
//
#include <hip/hip_runtime.h>
#include <math.h>

#define N_USERS 60000
#define N_ITEMS 30000
#define N_NODES 90000
#define DD 64
#define FF 192              // 3*DD
#define FH 96               // FF/2 (bf16 pairs per row)
#define KK_TOT 1408         // 768 + 512 + 128
#define E_UND 500000
#define E_DIR 1000000
#define SCAN_NBLK 88        // ceil(90000/1024)

typedef __attribute__((ext_vector_type(8))) __bf16 bf16x8;
typedef __attribute__((ext_vector_type(8))) unsigned short u16x8;
typedef __attribute__((ext_vector_type(4))) float f32x4;

typedef __attribute__((address_space(1))) const void gvoid;
typedef __attribute__((address_space(3))) void svoid;

__device__ __forceinline__ void gll16(const void* g, void* l) {
    // async global->LDS DMA, 16B per lane; LDS dest = uniform base + lane*16
    __builtin_amdgcn_global_load_lds((gvoid*)g, (svoid*)l, 16, 0, 0);
}
__device__ __forceinline__ void fence_bar() {
    asm volatile("" ::: "memory");
    __builtin_amdgcn_s_barrier();
    asm volatile("" ::: "memory");
}

__device__ __forceinline__ unsigned short f2bf(float f) {
    unsigned int u = __float_as_uint(f);
    unsigned int r = (u + 0x7FFFu + ((u >> 16) & 1u)) >> 16;   // RNE
    return (unsigned short)r;
}
__device__ __forceinline__ float bf_lo(unsigned int x) { return __uint_as_float(x << 16); }
__device__ __forceinline__ float bf_hi(unsigned int x) { return __uint_as_float(x & 0xFFFF0000u); }
__device__ __forceinline__ float bf2f(unsigned short x) {
    return __uint_as_float((unsigned int)x << 16);
}
__device__ __forceinline__ unsigned int pack2(float a, float b) {
    return ((unsigned int)f2bf(b) << 16) | (unsigned int)f2bf(a);
}

// ---------------- edge-layout probe: int32 vs int64 storage ----------------
__global__ void k_mode(const int* __restrict__ ei, int* __restrict__ mode) {
    __shared__ int any;
    if (threadIdx.x == 0) any = 0;
    __syncthreads();
    if (ei[2 * threadIdx.x + 1] != 0) atomicOr(&any, 1);
    __syncthreads();
    if (threadIdx.x == 0) mode[0] = (any == 0) ? 1 : 0;   // 1 => int64 layout
}

__device__ __forceinline__ void load_pair(const int* __restrict__ ei, int md, int u,
                                          int& a, int& b) {
    if (md) { a = ei[2 * u]; b = ei[2 * (E_UND + u)]; }
    else    { a = ei[u];     b = ei[E_UND + u]; }
}

// ---------------- degree count ----------------
__global__ void k_deg(const int* __restrict__ ei, const int* __restrict__ mode,
                      int* __restrict__ deg) {
    int i = blockIdx.x * 256 + threadIdx.x;
    if (i >= E_UND) return;
    int md = mode[0];
    int a, b;
    load_pair(ei, md, i, a, b);
    atomicAdd(&deg[a], 1);
    atomicAdd(&deg[b], 1);
}

// ---------------- exclusive scan (3 kernels) ----------------
__global__ __launch_bounds__(1024) void k_scan1(const int* __restrict__ deg,
                                                int* __restrict__ offs,
                                                int* __restrict__ bsum) {
    __shared__ int tmp[1024];
    int b = blockIdx.x, t = threadIdx.x;
    int i = b * 1024 + t;
    int v = (i < N_NODES) ? deg[i] : 0;
    tmp[t] = v;
    __syncthreads();
    for (int off = 1; off < 1024; off <<= 1) {
        int add = (t >= off) ? tmp[t - off] : 0;
        __syncthreads();
        tmp[t] += add;
        __syncthreads();
    }
    offs[i] = tmp[t] - v;              // exclusive within block
    if (t == 1023) bsum[b] = tmp[t];
}

__global__ void k_scan2(const int* __restrict__ bsum, int* __restrict__ bscan) {
    if (threadIdx.x == 0) {
        int run = 0;
        for (int b = 0; b < SCAN_NBLK; b++) { bscan[b] = run; run += bsum[b]; }
    }
}

__global__ void k_scan3(const int* __restrict__ deg, int* __restrict__ offs,
                        const int* __restrict__ bscan, int* __restrict__ cursor,
                        float* __restrict__ rsq) {
    int i = blockIdx.x * 256 + threadIdx.x;
    if (i >= N_NODES) return;
    int o = offs[i] + bscan[i >> 10];
    offs[i] = o;
    cursor[i] = o;
    int dg = deg[i];
    if (dg < 1) dg = 1;
    rsq[i] = rsqrtf((float)dg);
}

// ---------------- CSR fill (counting-sort scatter) ----------------
__global__ void k_fill(const int* __restrict__ ei, const int* __restrict__ mode,
                       int* __restrict__ cursor, const float* __restrict__ rsq,
                       int* __restrict__ edst, float* __restrict__ eval) {
    int i = blockIdx.x * 256 + threadIdx.x;
    if (i >= E_DIR) return;
    int md = mode[0];
    int u = (i < E_UND) ? i : i - E_UND;
    int a, b;
    load_pair(ei, md, u, a, b);
    int s, d;
    if (i < E_UND) { s = a; d = b; } else { s = b; d = a; }
    int slot = atomicAdd(&cursor[s], 1);
    edst[slot] = d;
    eval[slot] = rsq[s] * rsq[d];
}

// ---------------- user rows: transpose copy into bf16 Xb ----------------
__global__ void k_users(const float* __restrict__ ue, unsigned short* __restrict__ Xbs) {
    int idx = blockIdx.x * 256 + threadIdx.x;
    if (idx >= N_USERS * FF) return;
    int n = idx / FF;
    int r = idx - n * FF;
    int b = r >> 6, d = r & 63;
    Xbs[idx] = f2bf(ue[((size_t)b * N_USERS + n) * DD + d]);
}

// ---------------- W transpose+concat+bf16: Wtb[n][k], n=b*64+d ----------------
__global__ void k_cvt_w(const float* __restrict__ Wt, const float* __restrict__ Wi,
                        const float* __restrict__ Wst, unsigned short* __restrict__ Wtb) {
    int idx = blockIdx.x * 256 + threadIdx.x;
    if (idx >= FF * KK_TOT) return;
    int n = idx / KK_TOT;
    int k = idx - n * KK_TOT;
    int b = n >> 6, d = n & 63;
    float v;
    if (k < 768)       v = Wt [((size_t)b * 768 + k) * 64 + d];
    else if (k < 1280) v = Wi [((size_t)b * 512 + (k - 768)) * 64 + d];
    else               v = Wst[((size_t)b * 128 + (k - 1280)) * 64 + d];
    Wtb[idx] = f2bf(v);
}

// ---------------- W1 transpose to bf16: W1T[n][k] = W1[k][n], 128x192 -------
__global__ void k_cvt_w1(const float* __restrict__ Wu1, const float* __restrict__ Wi1,
                         unsigned short* __restrict__ W1Tu,
                         unsigned short* __restrict__ W1Ti) {
    int idx = blockIdx.x * 256 + threadIdx.x;
    if (idx >= 128 * FF) return;
    int n = idx / FF;
    int k = idx - n * FF;
    W1Tu[idx] = f2bf(Wu1[(size_t)k * 128 + n]);
    W1Ti[idx] = f2bf(Wi1[(size_t)k * 128 + n]);
}

// ---------------- item feature GEMM ----------------
// 64x192 tile per block, 8 waves (512 thr). global_load_lds(16B) staging,
// double-buffered, counted s_waitcnt vmcnt(5) + raw s_barrier so tile t+1's
// loads stay in flight across the whole compute(t) phase (T3/T4). A staged
// fp32 (no pre-convert possible in DMA), converted to bf16 at frag read.
// Both LDS tiles XOR chunk-swizzled via pre-swizzled GLOBAL source (T2,
// rule #21) so ds_read_b128 fragments are bank-conflict-free.
#define BM 64
#define BK 64
#define NT (KK_TOT / BK)    // 22

__global__ __launch_bounds__(512, 4) void k_item_gemm_mfma3(
    const float* __restrict__ xt, const float* __restrict__ xi, const float* __restrict__ xs,
    const unsigned short* __restrict__ Wtb,
    const float* __restrict__ bt, const float* __restrict__ bi, const float* __restrict__ bst,
    unsigned short* __restrict__ Xbs) {
    __shared__ float          Ashf[2][BM * BK];   // 2 x 16 KB, fp32, chunk-swizzled
    __shared__ unsigned short Bsh [2][FF * BK];   // 2 x 24 KB, bf16, chunk-swizzled
    const int tid  = threadIdx.x;
    const int w    = tid >> 6;          // 0..7
    const int lane = tid & 63;
    const int row0 = blockIdx.x * BM;
    const int l16  = lane & 15;
    const int quad = lane >> 4;
    const int rg   = w & 3;             // row group (16 rows)
    const int ng   = w >> 2;            // N half (96 cols)

    // staging: wave w stages A rows [w*8, w*8+8) (2 instrs) and
    // B rows [w*24, w*24+24) (3 instrs); each instr = 64 lanes x 16B = 1KB
    const int ac = lane & 15;           // A 16B-chunk within 256B row
    const int bc = lane & 7;            // B 16B-chunk within 128B row

    auto stage = [&](int k0, int buf) {
#pragma unroll
        for (int i = 0; i < 2; i++) {
            int rb = w * 8 + i * 4;                 // uniform row base
            int r  = rb + (lane >> 4);
            int gr = row0 + r; if (gr >= N_ITEMS) gr = N_ITEMS - 1;
            const float* rp;
            if (k0 < 768)       rp = xt + (size_t)gr * 768 + k0;
            else if (k0 < 1280) rp = xi + (size_t)gr * 512 + (k0 - 768);
            else                rp = xs + (size_t)gr * 128 + (k0 - 1280);
            // pre-swizzled source: orig chunk c lands at LDS slot c^(r&15)
            gll16(rp + ((ac ^ (r & 15)) << 2), &Ashf[buf][rb * BK]);
        }
#pragma unroll
        for (int j = 0; j < 3; j++) {
            int rb = w * 24 + j * 8;                // uniform row base
            int r  = rb + (lane >> 3);
            gll16(Wtb + (size_t)r * KK_TOT + k0 + ((bc ^ (r & 7)) << 3),
                  &Bsh[buf][rb * BK]);
        }
    };

    f32x4 acc[6];
#pragma unroll
    for (int tn = 0; tn < 6; tn++) acc[tn] = (f32x4){0.f, 0.f, 0.f, 0.f};

    auto compute = [&](int buf) {
#pragma unroll
        for (int kk = 0; kk < BK; kk += 32) {
            const int rA = rg * 16 + l16;           // rA & 15 == l16
            const float* Ab = &Ashf[buf][rA * BK];
            const int c0 = (kk >> 2) + quad * 2;    // 16B chunk of k=kk+quad*8
            float4 a0 = *(const float4*)(Ab + (((c0    ) ^ l16) << 2));
            float4 a1 = *(const float4*)(Ab + (((c0 + 1) ^ l16) << 2));
            bf16x8 af;
            af[0] = (__bf16)a0.x; af[1] = (__bf16)a0.y;
            af[2] = (__bf16)a0.z; af[3] = (__bf16)a0.w;
            af[4] = (__bf16)a1.x; af[5] = (__bf16)a1.y;
            af[6] = (__bf16)a1.z; af[7] = (__bf16)a1.w;
            const int cB = (kk >> 3) + quad;
#pragma unroll
            for (int tn = 0; tn < 6; tn++) {
                int R = ng * 96 + tn * 16 + l16;    // R & 7 == l16 & 7
                bf16x8 bfrag = *(const bf16x8*)(&Bsh[buf][R * BK + ((cB ^ (R & 7)) << 3)]);
                acc[tn] = __builtin_amdgcn_mfma_f32_16x16x32_bf16(af, bfrag, acc[tn], 0, 0, 0);
            }
        }
    };

    stage(0, 0);
    int cur = 0;
#pragma unroll 1
    for (int t = 0; t < NT - 1; ++t) {
        fence_bar();                         // all waves done reading buf^1 (compute t-1)
        stage((t + 1) * BK, cur ^ 1);        // 5 gll per wave, stay in flight
        asm volatile("s_waitcnt vmcnt(5)" ::: "memory");   // own tile-t loads landed
        fence_bar();                         // all waves' tile-t loads landed
        compute(cur);
        cur ^= 1;
    }
    fence_bar();
    asm volatile("s_waitcnt vmcnt(0)" ::: "memory");
    fence_bar();
    compute(cur);

    // epilogue: bias + bf16 store
#pragma unroll
    for (int tn = 0; tn < 6; tn++) {
        int n = ng * 96 + tn * 16 + l16;    // 0..191
        int b = n >> 6, d = n & 63;
        float bias = bt[b * 64 + d] + bi[b * 64 + d] + bst[b * 64 + d];
#pragma unroll
        for (int r = 0; r < 4; r++) {
            int row = row0 + rg * 16 + quad * 4 + r;
            if (row < N_ITEMS) {
                Xbs[(size_t)(N_USERS + row) * FF + n] = f2bf(acc[tn][r] + bias);
            }
        }
    }
}

// ---------------- SPMM bf16 gather, 4-wide unroll ----------------
__global__ __launch_bounds__(192) void k_spmm_bf(const unsigned int* __restrict__ Xb,
                                                 unsigned int* __restrict__ Yb,
                                                 const int* __restrict__ offs,
                                                 const int* __restrict__ deg,
                                                 const int* __restrict__ edst,
                                                 const float* __restrict__ eval) {
    int t = threadIdx.x;
    int half = (t >= FH) ? 1 : 0;
    int c = t - half * FH;
    int n = blockIdx.x * 2 + half;
    int start = offs[n];
    int dg = deg[n];
    const int* ed = edst + start;
    const float* ev = eval + start;
    float a0 = 0.f, a1 = 0.f;
    for (int j = 0; j < dg; j += 4) {
        int last = dg - 1;
        int j1 = (j + 1 < dg) ? j + 1 : last;
        int j2 = (j + 2 < dg) ? j + 2 : last;
        int j3 = (j + 3 < dg) ? j + 3 : last;
        int d0 = ed[j], d1 = ed[j1], d2 = ed[j2], d3 = ed[j3];
        float v0 = ev[j];
        float v1 = (j + 1 < dg) ? ev[j1] : 0.f;
        float v2 = (j + 2 < dg) ? ev[j2] : 0.f;
        float v3 = (j + 3 < dg) ? ev[j3] : 0.f;
        unsigned int x0 = Xb[(size_t)d0 * FH + c];
        unsigned int x1 = Xb[(size_t)d1 * FH + c];
        unsigned int x2 = Xb[(size_t)d2 * FH + c];
        unsigned int x3 = Xb[(size_t)d3 * FH + c];
        a0 = fmaf(v0, bf_lo(x0), a0); a1 = fmaf(v0, bf_hi(x0), a1);
        a0 = fmaf(v1, bf_lo(x1), a0); a1 = fmaf(v1, bf_hi(x1), a1);
        a0 = fmaf(v2, bf_lo(x2), a0); a1 = fmaf(v2, bf_hi(x2), a1);
        a0 = fmaf(v3, bf_lo(x3), a0); a1 = fmaf(v3, bf_hi(x3), a1);
    }
    Yb[(size_t)n * FH + c] = pack2(a0, a1);
}

// ---------------- attention: sum 3 bf16 layers + MFMA MLP + readout --------
#define LDA 200

__global__ __launch_bounds__(256) void k_attn_mfma(
    const unsigned int* __restrict__ X0,      // layer-0 bf16 pairs
    const unsigned int* __restrict__ X1,      // layer-1
    const unsigned int* __restrict__ X2,      // layer-2
    const unsigned short* __restrict__ W1T,   // 128 x 192 bf16 (pre-transposed)
    const float* __restrict__ B1,             // 128
    const float* __restrict__ W2,             // 128 x 3
    const float* __restrict__ B2,             // 3
    float* __restrict__ out,
    int node_base, int n_rows) {
    __shared__ unsigned short Atile[64 * LDA];
    __shared__ float aws[64][4];
    const int tid  = threadIdx.x;
    const int wave = tid >> 6;
    const int lane = tid & 63;
    const int row0 = blockIdx.x * 64;
    const float inv3 = 1.f / 3.f;

    // stage A: 64 rows x 96 uint-pairs; sum three bf16 layers in fp32, /3
#pragma unroll
    for (int i = 0; i < 6; i++) {
        int id = tid + i * 256;            // 0..1535
        int r = id / 24;
        int q = id - r * 24;               // uint group: 4 uints = 8 bf16 cols
        u16x8 pk;
        if (row0 + r < n_rows) {
            size_t base = (size_t)(node_base + row0 + r) * FH + q * 4;
            uint4 a = *(const uint4*)(X0 + base);
            uint4 b = *(const uint4*)(X1 + base);
            uint4 c = *(const uint4*)(X2 + base);
            pk[0] = f2bf((bf_lo(a.x) + bf_lo(b.x) + bf_lo(c.x)) * inv3);
            pk[1] = f2bf((bf_hi(a.x) + bf_hi(b.x) + bf_hi(c.x)) * inv3);
            pk[2] = f2bf((bf_lo(a.y) + bf_lo(b.y) + bf_lo(c.y)) * inv3);
            pk[3] = f2bf((bf_hi(a.y) + bf_hi(b.y) + bf_hi(c.y)) * inv3);
            pk[4] = f2bf((bf_lo(a.z) + bf_lo(b.z) + bf_lo(c.z)) * inv3);
            pk[5] = f2bf((bf_hi(a.z) + bf_hi(b.z) + bf_hi(c.z)) * inv3);
            pk[6] = f2bf((bf_lo(a.w) + bf_lo(b.w) + bf_lo(c.w)) * inv3);
            pk[7] = f2bf((bf_hi(a.w) + bf_hi(b.w) + bf_hi(c.w)) * inv3);
        } else {
            pk = (u16x8){0, 0, 0, 0, 0, 0, 0, 0};
        }
        *(u16x8*)(&Atile[r * LDA + q * 8]) = pk;
    }
    __syncthreads();

    f32x4 acc[8];
#pragma unroll
    for (int tn = 0; tn < 8; tn++) acc[tn] = (f32x4){0.f, 0.f, 0.f, 0.f};
    const int l16 = lane & 15;
    const int quad = lane >> 4;
#pragma unroll
    for (int kk = 0; kk < FF; kk += 32) {
        bf16x8 af = *(const bf16x8*)(&Atile[(wave * 16 + l16) * LDA + kk + quad * 8]);
#pragma unroll
        for (int tn = 0; tn < 8; tn++) {
            bf16x8 bf = *(const bf16x8*)(&W1T[(size_t)(tn * 16 + l16) * FF + kk + quad * 8]);
            acc[tn] = __builtin_amdgcn_mfma_f32_16x16x32_bf16(af, bf, acc[tn], 0, 0, 0);
        }
    }

    float pl[4][3];
#pragma unroll
    for (int r = 0; r < 4; r++) { pl[r][0] = 0.f; pl[r][1] = 0.f; pl[r][2] = 0.f; }
#pragma unroll
    for (int tn = 0; tn < 8; tn++) {
        int col = tn * 16 + l16;
        float b1v = B1[col];
        float w0 = W2[col * 3 + 0], w1 = W2[col * 3 + 1], w2v = W2[col * 3 + 2];
#pragma unroll
        for (int r = 0; r < 4; r++) {
            float h = fmaxf(acc[tn][r] + b1v, 0.f);
            pl[r][0] = fmaf(h, w0, pl[r][0]);
            pl[r][1] = fmaf(h, w1, pl[r][1]);
            pl[r][2] = fmaf(h, w2v, pl[r][2]);
        }
    }
#pragma unroll
    for (int m = 1; m <= 8; m <<= 1) {
#pragma unroll
        for (int r = 0; r < 4; r++) {
            pl[r][0] += __shfl_xor(pl[r][0], m, 64);
            pl[r][1] += __shfl_xor(pl[r][1], m, 64);
            pl[r][2] += __shfl_xor(pl[r][2], m, 64);
        }
    }
    float b20 = B2[0], b21 = B2[1], b22 = B2[2];
    if (l16 == 0) {
#pragma unroll
        for (int r = 0; r < 4; r++) {
            float l0 = pl[r][0] + b20, l1 = pl[r][1] + b21, l2 = pl[r][2] + b22;
            float mx = fmaxf(l0, fmaxf(l1, l2));
            float e0 = __expf(l0 - mx), e1 = __expf(l1 - mx), e2 = __expf(l2 - mx);
            float inv = 1.f / (e0 + e1 + e2);
            int rr = wave * 16 + quad * 4 + r;
            aws[rr][0] = e0 * inv; aws[rr][1] = e1 * inv; aws[rr][2] = e2 * inv;
        }
    }
    __syncthreads();

#pragma unroll
    for (int i = 0; i < 16; i++) {
        int flat = tid + i * 256;
        int r = flat >> 6, d = flat & 63;
        if (row0 + r < n_rows) {
            float a0 = aws[r][0], a1 = aws[r][1], a2 = aws[r][2];
            const unsigned short* Ar = &Atile[r * LDA];
            float v = a0 * bf2f(Ar[d]) + a1 * bf2f(Ar[64 + d]) + a2 * bf2f(Ar[128 + d]);
            out[(size_t)(node_base + row0 + r) * DD + d] = v;
        }
    }
}

// ---------------- launch ----------------
extern "C" void kernel_launch(void* const* d_in, const int* in_sizes, int n_in,
                              void* d_out, int out_size, void* d_ws, size_t ws_size,
                              hipStream_t stream) {
    (void)in_sizes; (void)n_in; (void)out_size; (void)ws_size;
    const float* x_txt    = (const float*)d_in[0];
    const float* x_img    = (const float*)d_in[1];
    const float* x_struct = (const float*)d_in[2];
    const float* user_emb = (const float*)d_in[3];
    const float* W_txt    = (const float*)d_in[4];
    const float* b_txt    = (const float*)d_in[5];
    const float* W_img    = (const float*)d_in[6];
    const float* b_img    = (const float*)d_in[7];
    const float* W_st     = (const float*)d_in[8];
    const float* b_st     = (const float*)d_in[9];
    const float* Wu1      = (const float*)d_in[10];
    const float* bu1      = (const float*)d_in[11];
    const float* Wu2      = (const float*)d_in[12];
    const float* bu2      = (const float*)d_in[13];
    const float* Wi1      = (const float*)d_in[14];
    const float* bi1      = (const float*)d_in[15];
    const float* Wi2      = (const float*)d_in[16];
    const float* bi2      = (const float*)d_in[17];
    const int*   ei       = (const int*)d_in[18];
    float* out = (float*)d_out;

    char* base = (char*)d_ws;
    size_t off = 0;
    auto take = [&](size_t bytes) -> void* {
        void* p = base + off;
        off += (bytes + 255) & ~(size_t)255;
        return p;
    };
    unsigned int* Xb0  = (unsigned int*)take((size_t)N_NODES * FH * 4);
    unsigned int* Yb   = (unsigned int*)take((size_t)N_NODES * FH * 4);
    unsigned int* Zb   = (unsigned int*)take((size_t)N_NODES * FH * 4);
    int* deg    = (int*)take((size_t)N_NODES * 4);
    int* offs   = (int*)take((size_t)SCAN_NBLK * 1024 * 4);
    int* cursor = (int*)take((size_t)N_NODES * 4);
    int* bsum   = (int*)take((size_t)SCAN_NBLK * 4);
    int* bscan  = (int*)take((size_t)SCAN_NBLK * 4);
    float* rsq  = (float*)take((size_t)N_NODES * 4);
    int* edst   = (int*)take((size_t)E_DIR * 4);
    float* eval = (float*)take((size_t)E_DIR * 4);
    int* mode   = (int*)take(256);
    unsigned short* Wtb  = (unsigned short*)take((size_t)FF * KK_TOT * 2);
    unsigned short* W1Tu = (unsigned short*)take((size_t)128 * FF * 2);
    unsigned short* W1Ti = (unsigned short*)take((size_t)128 * FF * 2);

    hipMemsetAsync(deg, 0, (size_t)N_NODES * 4, stream);

    k_mode<<<1, 256, 0, stream>>>(ei, mode);
    k_deg<<<(E_UND + 255) / 256, 256, 0, stream>>>(ei, mode, deg);
    k_scan1<<<SCAN_NBLK, 1024, 0, stream>>>(deg, offs, bsum);
    k_scan2<<<1, 64, 0, stream>>>(bsum, bscan);
    k_scan3<<<(N_NODES + 255) / 256, 256, 0, stream>>>(deg, offs, bscan, cursor, rsq);
    k_fill<<<(E_DIR + 255) / 256, 256, 0, stream>>>(ei, mode, cursor, rsq, edst, eval);

    k_users<<<(N_USERS * FF + 255) / 256, 256, 0, stream>>>(user_emb,
                                                            (unsigned short*)Xb0);
    k_cvt_w<<<(FF * KK_TOT + 255) / 256, 256, 0, stream>>>(W_txt, W_img, W_st, Wtb);
    k_cvt_w1<<<(128 * FF + 255) / 256, 256, 0, stream>>>(Wu1, Wi1, W1Tu, W1Ti);
    k_item_gemm_mfma3<<<(N_ITEMS + BM - 1) / BM, 512, 0, stream>>>(
        x_txt, x_img, x_struct, Wtb, b_txt, b_img, b_st, (unsigned short*)Xb0);

    k_spmm_bf<<<N_NODES / 2, 192, 0, stream>>>(Xb0, Yb, offs, deg, edst, eval);
    k_spmm_bf<<<N_NODES / 2, 192, 0, stream>>>(Yb, Zb, offs, deg, edst, eval);

    k_attn_mfma<<<(N_USERS + 63) / 64, 256, 0, stream>>>(
        Xb0, Yb, Zb, W1Tu, bu1, Wu2, bu2, out, 0, N_USERS);
    k_attn_mfma<<<(N_ITEMS + 63) / 64, 256, 0, stream>>>(
        Xb0, Yb, Zb, W1Ti, bi1, Wi2, bi2, out, N_USERS, N_ITEMS);
}